// Round 3
// baseline (661.025 us; speedup 1.0000x reference)
//
#include <hip/hip_runtime.h>
#include <math.h>

#define NEG_SLOPE 0.2f
#define EPS_F 1e-16f
typedef long long ll;

typedef __attribute__((ext_vector_type(4))) float f32x4;
typedef __attribute__((ext_vector_type(8))) short bf16x8;

// ---------------- bf16 helpers (bit-level, RTN-even) ----------------
__device__ __forceinline__ unsigned short bf16_of(float f) {
  unsigned u = __float_as_uint(f);
  u += 0x7fffu + ((u >> 16) & 1u);
  return (unsigned short)(u >> 16);
}
__device__ __forceinline__ float bf16_back(unsigned short s) {
  return __uint_as_float((unsigned)s << 16);
}

__device__ __forceinline__ void gload16(const void* g, void* l) {
  __builtin_amdgcn_global_load_lds((const __attribute__((address_space(1))) void*)g,
                                   (__attribute__((address_space(3))) void*)l, 16, 0, 0);
}

// ---------------- edge dtype detection (int64 vs int32) ----------------
__global__ void detect_int64_kernel(const unsigned int* __restrict__ w, int E,
                                    int* __restrict__ flag) {
  __shared__ int nz;
  if (threadIdx.x == 0) nz = 0;
  __syncthreads();
  int cnt = E < 2048 ? E : 2048;
  int local = 0;
  for (int i = threadIdx.x; i < cnt; i += blockDim.x)
    if (w[2 * i + 1] != 0u) local++;
  if (local) atomicAdd(&nz, local);
  __syncthreads();
  if (threadIdx.x == 0) *flag = (nz == 0) ? 1 : 0;  // 1 => int64 layout
}

__device__ __forceinline__ void edge_at(const int* __restrict__ ew, int E, int e,
                                        int is64, int& s, int& d) {
  if (is64) { s = ew[2 * e]; d = ew[2 * E + 2 * e]; }
  else      { s = ew[e];     d = ew[E + e]; }
}

// ---------------- CSR build ----------------
__global__ void init_deg_kernel(int* deg, int N) {
  int i = blockIdx.x * blockDim.x + threadIdx.x;
  if (i < N) deg[i] = 1;  // self loop
}

__global__ void count_deg_kernel(const int* __restrict__ ew, int E, int* deg,
                                 const int* __restrict__ flag) {
  int is64 = *flag;
  int e = blockIdx.x * blockDim.x + threadIdx.x;
  if (e < E) {
    int s, d;
    edge_at(ew, E, e, is64, s, d);
    atomicAdd(&deg[d], 1);
  }
}

__global__ void scan_kernel(const int* __restrict__ deg, int* rowptr, int* cursor, int N) {
  __shared__ int sums[1024];
  int tid = threadIdx.x;
  int chunk = (N + 1023) >> 10;
  int start = tid * chunk;
  int end = start + chunk; if (end > N) end = N;
  int s = 0;
  for (int i = start; i < end; ++i) s += deg[i];
  sums[tid] = s;
  __syncthreads();
  for (int off = 1; off < 1024; off <<= 1) {
    int v = (tid >= off) ? sums[tid - off] : 0;
    __syncthreads();
    sums[tid] += v;
    __syncthreads();
  }
  int run = (tid == 0) ? 0 : sums[tid - 1];
  for (int i = start; i < end; ++i) {
    rowptr[i] = run; cursor[i] = run;
    run += deg[i];
  }
  if (tid == 1023) rowptr[N] = sums[1023];
}

__global__ void fill_kernel(const int* __restrict__ ew, int E, int N, int* cursor,
                            int* csr, const int* __restrict__ flag) {
  int is64 = *flag;
  int i = blockIdx.x * blockDim.x + threadIdx.x;
  if (i < E) {
    int s, d;
    edge_at(ew, E, i, is64, s, d);
    int pos = atomicAdd(&cursor[d], 1);
    csr[pos] = s;
  } else if (i < E + N) {
    int n = i - E;
    int pos = atomicAdd(&cursor[n], 1);
    csr[pos] = n;
  }
}

// ---------------- input conversions to split-bf16 ----------------
__global__ void convert_x_kernel(const float* __restrict__ x, short* __restrict__ A, int N) {
  int i = blockIdx.x * blockDim.x + threadIdx.x;
  if (i >= N * 256) return;
  int r = i >> 8, c = i & 255;
  float v = x[i];
  unsigned short hi = bf16_of(v);
  unsigned short lo = bf16_of(v - bf16_back(hi));
  A[(ll)r * 512 + c] = (short)hi;
  A[(ll)r * 512 + 256 + c] = (short)lo;
}

// W [K, Nc] fp32 -> Bt [Nc, 3K] bf16: segs [0,K)=W_hi^T, [K,2K)=W_lo^T, [2K,3K)=W_hi^T
__global__ __launch_bounds__(256) void convert_w_kernel(const float* __restrict__ W,
                                                        short* __restrict__ Bt,
                                                        int K, int Nc) {
  __shared__ float t[32][33];
  int k0 = blockIdx.x * 32, n0 = blockIdx.y * 32;
  int r = threadIdx.x >> 3;          // 0..31
  int c4 = (threadIdx.x & 7) * 4;    // 0..28
  float4 v = *(const float4*)&W[(ll)(k0 + r) * Nc + n0 + c4];
  t[r][c4] = v.x; t[r][c4 + 1] = v.y; t[r][c4 + 2] = v.z; t[r][c4 + 3] = v.w;
  __syncthreads();
  int K3 = 3 * K;
  short4 hp, lp;
  float f0 = t[c4 + 0][r], f1 = t[c4 + 1][r], f2 = t[c4 + 2][r], f3 = t[c4 + 3][r];
  unsigned short h0 = bf16_of(f0), h1 = bf16_of(f1), h2 = bf16_of(f2), h3 = bf16_of(f3);
  hp = make_short4((short)h0, (short)h1, (short)h2, (short)h3);
  lp = make_short4((short)bf16_of(f0 - bf16_back(h0)), (short)bf16_of(f1 - bf16_back(h1)),
                   (short)bf16_of(f2 - bf16_back(h2)), (short)bf16_of(f3 - bf16_back(h3)));
  ll base = (ll)(n0 + r) * K3 + k0 + c4;
  *(short4*)&Bt[base] = hp;
  *(short4*)&Bt[base + K] = lp;
  *(short4*)&Bt[base + 2 * K] = hp;
}

// ---------------- MFMA GEMM: C[M,Nc] = A''(split) x Bt^T ----------------
// A: [M, 2K] bf16 ([hi|lo]); Bt: [Nc, 3K] bf16; effective K' = 3K.
// LDS layout: [k-chunk(4)][row(128)][16B] -> conflict-free ds_read_b128 fragments.
// Staging keeps LDS dst linear (= tid*16); the GLOBAL source is permuted
// (row = tid&127, chunk = tid>>7) per the both-sides-or-neither rule.
template <int HBF16>
__global__ __launch_bounds__(256) void gemm_mfma_kernel(
    const short* __restrict__ A, const short* __restrict__ Bt,
    void* __restrict__ Cv, int M, int Nc, int K) {
  __shared__ char As[8192];
  __shared__ char Bs[8192];
  int tid = threadIdx.x;
  int bm = blockIdx.y * 128, bn = blockIdx.x * 128;
  int lane = tid & 63, wid = tid >> 6;
  int wr = wid >> 1, wc = wid & 1;
  int K2 = 2 * K, K3 = 3 * K;

  f32x4 acc[4][4];
#pragma unroll
  for (int m = 0; m < 4; ++m)
#pragma unroll
    for (int n = 0; n < 4; ++n) acc[m][n] = (f32x4){0.f, 0.f, 0.f, 0.f};

  int srow = tid & 127;           // staged row within tile
  int sc = (tid >> 7) * 8;        // k-chunk bf16 offset (chunk 0/1; +16 for 2/3)
  int ra = bm + srow; if (ra > M - 1) ra = M - 1;
  int rb = bn + srow; if (Nc == 128) rb = bn + (srow & 127);  // Nc>=128 always
  const short* aP = A + (ll)ra * K2 + sc;
  const short* bP = Bt + (ll)rb * K3 + sc;
  char* asDst = As + tid * 16;
  char* bsDst = Bs + tid * 16;

  const char* aF0 = As + (lane >> 4) * 2048 + (wr * 64 + (lane & 15)) * 16;
  const char* bF0 = Bs + (lane >> 4) * 2048 + (wc * 64 + (lane & 15)) * 16;

  for (int kt = 0; kt < K3; kt += 32) {
    int akt = kt < K ? kt : kt - K;  // A: hi,hi,lo per segment
    gload16(aP + akt, asDst);
    gload16(aP + akt + 16, asDst + 4096);
    gload16(bP + kt, bsDst);
    gload16(bP + kt + 16, bsDst + 4096);
    __syncthreads();
    bf16x8 af[4], bfr[4];
#pragma unroll
    for (int m = 0; m < 4; ++m) af[m] = *(const bf16x8*)(aF0 + m * 256);
#pragma unroll
    for (int n = 0; n < 4; ++n) bfr[n] = *(const bf16x8*)(bF0 + n * 256);
#pragma unroll
    for (int m = 0; m < 4; ++m)
#pragma unroll
      for (int n = 0; n < 4; ++n)
        acc[m][n] = __builtin_amdgcn_mfma_f32_16x16x32_bf16(af[m], bfr[n], acc[m][n], 0, 0, 0);
    __syncthreads();
  }

  int crow0 = bm + wr * 64 + (lane >> 4) * 4;
  int ccol0 = bn + wc * 64 + (lane & 15);
#pragma unroll
  for (int m = 0; m < 4; ++m) {
#pragma unroll
    for (int j = 0; j < 4; ++j) {
      int row = crow0 + m * 16 + j;
      if (row < M) {
#pragma unroll
        for (int n = 0; n < 4; ++n) {
          if (HBF16) ((unsigned short*)Cv)[(ll)row * Nc + ccol0 + n * 16] = bf16_of(acc[m][n][j]);
          else       ((float*)Cv)[(ll)row * Nc + ccol0 + n * 16] = acc[m][n][j];
        }
      }
    }
  }
}

// ---------------- per-node attention scores ----------------
template <int HBF16>
__global__ void score_kernel(const void* __restrict__ hv, const float* __restrict__ a_src,
                             const float* __restrict__ a_dst, float* __restrict__ s_src,
                             float* __restrict__ s_dst, int N, int dout) {
  int wid = threadIdx.x >> 6;
  int lane = threadIdx.x & 63;
  int row = blockIdx.x * (blockDim.x >> 6) + wid;
  if (row >= N) return;
  const float4* as4 = (const float4*)a_src;
  const float4* ad4 = (const float4*)a_dst;
  float ss = 0.f, sd = 0.f;
  int nv = dout >> 2;
  if (HBF16) {
    const short4* hr = (const short4*)((const unsigned short*)hv + (ll)row * dout);
    for (int d = lane; d < nv; d += 64) {
      short4 q = hr[d];
      float4 a = as4[d], b = ad4[d];
      float x0 = bf16_back((unsigned short)q.x), x1 = bf16_back((unsigned short)q.y);
      float x2 = bf16_back((unsigned short)q.z), x3 = bf16_back((unsigned short)q.w);
      ss += x0 * a.x + x1 * a.y + x2 * a.z + x3 * a.w;
      sd += x0 * b.x + x1 * b.y + x2 * b.z + x3 * b.w;
    }
  } else {
    const float4* hr = (const float4*)((const float*)hv + (ll)row * dout);
    for (int d = lane; d < nv; d += 64) {
      float4 v = hr[d], a = as4[d], b = ad4[d];
      ss += v.x * a.x + v.y * a.y + v.z * a.z + v.w * a.w;
      sd += v.x * b.x + v.y * b.y + v.z * b.z + v.w * b.w;
    }
  }
#pragma unroll
  for (int o = 32; o > 0; o >>= 1) {
    ss += __shfl_xor(ss, o, 64);
    sd += __shfl_xor(sd, o, 64);
  }
  if (lane == 0) { s_src[row] = ss; s_dst[row] = sd; }
}

// ---------------- segment softmax + weighted aggregation (per node) ----------------
template <int HBF16>
__global__ __launch_bounds__(256) void aggregate_kernel(
    const void* __restrict__ hv, const float* __restrict__ ssrc,
    const float* __restrict__ sdst, const int* __restrict__ rowptr,
    const int* __restrict__ csr, const float* __restrict__ bias,
    float* __restrict__ outF, short* __restrict__ outH, int dout, int do_relu) {
  int node = blockIdx.x;
  int tid = threadIdx.x;
  int lane = tid & 63, wid = tid >> 6;
  int rs = rowptr[node], re = rowptr[node + 1];
  float sd = sdst[node];
  __shared__ float red[4];

  // pass 1: max logit
  float m = -1e30f;
  for (int i = rs + tid; i < re; i += 256) {
    float e = ssrc[csr[i]] + sd;
    e = e > 0.f ? e : NEG_SLOPE * e;
    m = fmaxf(m, e);
  }
#pragma unroll
  for (int o = 32; o > 0; o >>= 1) m = fmaxf(m, __shfl_xor(m, o, 64));
  if (lane == 0) red[wid] = m;
  __syncthreads();
  m = fmaxf(fmaxf(red[0], red[1]), fmaxf(red[2], red[3]));
  __syncthreads();

  // pass 2: denominator
  float den = 0.f;
  for (int i = rs + tid; i < re; i += 256) {
    float e = ssrc[csr[i]] + sd;
    e = e > 0.f ? e : NEG_SLOPE * e;
    den += __expf(e - m);
  }
#pragma unroll
  for (int o = 32; o > 0; o >>= 1) den += __shfl_xor(den, o, 64);
  if (lane == 0) red[wid] = den;
  __syncthreads();
  den = red[0] + red[1] + red[2] + red[3];
  float inv = 1.f / (den + EPS_F);

  // pass 3: weighted accumulate (4 dims per thread)
  int d = tid * 4;
  bool act = d < dout;
  float ax = 0.f, ay = 0.f, az = 0.f, aw = 0.f;
  for (int i = rs; i < re; ++i) {
    int s = csr[i];
    float e = ssrc[s] + sd;
    e = e > 0.f ? e : NEG_SLOPE * e;
    float w = __expf(e - m) * inv;
    if (act) {
      if (HBF16) {
        short4 q = *(const short4*)((const unsigned short*)hv + (ll)s * dout + d);
        ax += w * bf16_back((unsigned short)q.x);
        ay += w * bf16_back((unsigned short)q.y);
        az += w * bf16_back((unsigned short)q.z);
        aw += w * bf16_back((unsigned short)q.w);
      } else {
        float4 hvv = *(const float4*)((const float*)hv + (ll)s * dout + d);
        ax += w * hvv.x; ay += w * hvv.y; az += w * hvv.z; aw += w * hvv.w;
      }
    }
  }
  if (act) {
    float4 bv = *(const float4*)&bias[d];
    float vx = ax + bv.x, vy = ay + bv.y, vz = az + bv.z, vw = aw + bv.w;
    if (do_relu) {
      vx = fmaxf(vx, 0.f); vy = fmaxf(vy, 0.f);
      vz = fmaxf(vz, 0.f); vw = fmaxf(vw, 0.f);
    }
    if (outH) {
      unsigned short h0 = bf16_of(vx), h1 = bf16_of(vy), h2 = bf16_of(vz), h3 = bf16_of(vw);
      short4 hp = make_short4((short)h0, (short)h1, (short)h2, (short)h3);
      short4 lp = make_short4((short)bf16_of(vx - bf16_back(h0)),
                              (short)bf16_of(vy - bf16_back(h1)),
                              (short)bf16_of(vz - bf16_back(h2)),
                              (short)bf16_of(vw - bf16_back(h3)));
      ll base = (ll)node * (2 * dout) + d;
      *(short4*)&outH[base] = hp;
      *(short4*)&outH[base + dout] = lp;
    } else {
      *(float4*)&outF[(ll)node * dout + d] = make_float4(vx, vy, vz, vw);
    }
  }
}

// ---------------- row log_softmax (C == blockDim.x) ----------------
__global__ void log_softmax_kernel(const float* __restrict__ in, float* __restrict__ out,
                                   int C) {
  int row = blockIdx.x;
  int tid = threadIdx.x;
  int lane = tid & 63, wid = tid >> 6;
  __shared__ float red[2];
  float v = in[(ll)row * C + tid];
  float m = v;
#pragma unroll
  for (int o = 32; o > 0; o >>= 1) m = fmaxf(m, __shfl_xor(m, o, 64));
  if (lane == 0) red[wid] = m;
  __syncthreads();
  m = fmaxf(red[0], red[1]);
  __syncthreads();
  float ex = __expf(v - m);
  float s = ex;
#pragma unroll
  for (int o = 32; o > 0; o >>= 1) s += __shfl_xor(s, o, 64);
  if (lane == 0) red[wid] = s;
  __syncthreads();
  s = red[0] + red[1];
  out[(ll)row * C + tid] = v - m - logf(s);
}

// ---------------- launch ----------------
extern "C" void kernel_launch(void* const* d_in, const int* in_sizes, int n_in,
                              void* d_out, int out_size, void* d_ws, size_t ws_size,
                              hipStream_t stream) {
  const float* x = (const float*)d_in[0];
  const int* ew = (const int*)d_in[1];
  int N = in_sizes[0] / 256;
  int E = in_sizes[1] / 2;

  const float* W[4]   = {(const float*)d_in[2],  (const float*)d_in[6],
                         (const float*)d_in[10], (const float*)d_in[14]};
  const float* Asv[4] = {(const float*)d_in[3],  (const float*)d_in[7],
                         (const float*)d_in[11], (const float*)d_in[15]};
  const float* Adv[4] = {(const float*)d_in[4],  (const float*)d_in[8],
                         (const float*)d_in[12], (const float*)d_in[16]};
  const float* Bv[4]  = {(const float*)d_in[5],  (const float*)d_in[9],
                         (const float*)d_in[13], (const float*)d_in[17]};
  const int din[4]  = {256, 1024, 1024, 512};
  const int dout[4] = {1024, 1024, 512, 128};

  char* ws = (char*)d_ws;
  size_t off = 0;
  auto alloc = [&](size_t bytes) {
    void* p = ws + off;
    off += (bytes + 255) & ~(size_t)255;
    return p;
  };
  unsigned short* hB = (unsigned short*)alloc((size_t)N * 1024 * 2);  // bf16 h (layers 1-3)
  float* hF   = (float*)alloc((size_t)N * 128 * 4);                   // fp32 h (layer 4)
  short* bufP = (short*)alloc((size_t)N * 2048 * 2);
  short* bufQ = (short*)alloc((size_t)N * 2048 * 2);
  float* sF   = (float*)alloc((size_t)N * 128 * 4);
  float* s_src = (float*)alloc((size_t)N * 4);
  float* s_dst = (float*)alloc((size_t)N * 4);
  int* deg    = (int*)alloc((size_t)(N + 1) * 4);
  int* rowptr = (int*)alloc((size_t)(N + 1) * 4);
  int* cursor = (int*)alloc((size_t)(N + 1) * 4);
  int* csr    = (int*)alloc((size_t)(E + N) * 4);
  int* flag   = (int*)alloc(256);
  short* Bt[4];
  for (int l = 0; l < 4; ++l) Bt[l] = (short*)alloc((size_t)dout[l] * 3 * din[l] * 2);

  detect_int64_kernel<<<1, 256, 0, stream>>>((const unsigned int*)ew, E, flag);
  init_deg_kernel<<<(N + 255) / 256, 256, 0, stream>>>(deg, N);
  count_deg_kernel<<<(E + 255) / 256, 256, 0, stream>>>(ew, E, deg, flag);
  scan_kernel<<<1, 1024, 0, stream>>>(deg, rowptr, cursor, N);
  fill_kernel<<<(E + N + 255) / 256, 256, 0, stream>>>(ew, E, N, cursor, csr, flag);

  convert_x_kernel<<<(N * 256 + 255) / 256, 256, 0, stream>>>(x, bufP, N);
  for (int l = 0; l < 4; ++l) {
    dim3 cg(din[l] / 32, dout[l] / 32);
    convert_w_kernel<<<cg, 256, 0, stream>>>(W[l], Bt[l], din[l], dout[l]);
  }

  short* cur = bufP;
  short* nxt = bufQ;
  for (int l = 0; l < 4; ++l) {
    dim3 ggrid(dout[l] / 128, (N + 127) / 128);
    if (l < 3) {
      gemm_mfma_kernel<1><<<ggrid, 256, 0, stream>>>(cur, Bt[l], hB, N, dout[l], din[l]);
      score_kernel<1><<<(N + 3) / 4, 256, 0, stream>>>(hB, Asv[l], Adv[l], s_src, s_dst,
                                                       N, dout[l]);
      aggregate_kernel<1><<<N, 256, 0, stream>>>(hB, s_src, s_dst, rowptr, csr, Bv[l],
                                                 nullptr, nxt, dout[l], 1);
    } else {
      gemm_mfma_kernel<0><<<ggrid, 256, 0, stream>>>(cur, Bt[l], hF, N, dout[l], din[l]);
      score_kernel<0><<<(N + 3) / 4, 256, 0, stream>>>(hF, Asv[l], Adv[l], s_src, s_dst,
                                                       N, dout[l]);
      aggregate_kernel<0><<<N, 256, 0, stream>>>(hF, s_src, s_dst, rowptr, csr, Bv[l],
                                                 sF, nullptr, dout[l], 0);
    }
    short* t = cur; cur = nxt; nxt = t;
  }
  log_softmax_kernel<<<N, 128, 0, stream>>>(sF, (float*)d_out, 128);
}

// Round 4
// 522.867 us; speedup vs baseline: 1.2642x; 1.2642x over previous
//
#include <hip/hip_runtime.h>
#include <math.h>

#define NEG_SLOPE 0.2f
#define EPS_F 1e-16f
typedef long long ll;

typedef __attribute__((ext_vector_type(4))) float f32x4;
typedef __attribute__((ext_vector_type(8))) short bf16x8;

// ---------------- bf16 helpers (bit-level, RTN-even) ----------------
__device__ __forceinline__ unsigned short bf16_of(float f) {
  unsigned u = __float_as_uint(f);
  u += 0x7fffu + ((u >> 16) & 1u);
  return (unsigned short)(u >> 16);
}
__device__ __forceinline__ float bf16_back(unsigned short s) {
  return __uint_as_float((unsigned)s << 16);
}

__device__ __forceinline__ void gload16(const void* g, void* l) {
  __builtin_amdgcn_global_load_lds((const __attribute__((address_space(1))) void*)g,
                                   (__attribute__((address_space(3))) void*)l, 16, 0, 0);
}

// ---------------- edge dtype detection (int64 vs int32) ----------------
__global__ void detect_int64_kernel(const unsigned int* __restrict__ w, int E,
                                    int* __restrict__ flag) {
  __shared__ int nz;
  if (threadIdx.x == 0) nz = 0;
  __syncthreads();
  int cnt = E < 2048 ? E : 2048;
  int local = 0;
  for (int i = threadIdx.x; i < cnt; i += blockDim.x)
    if (w[2 * i + 1] != 0u) local++;
  if (local) atomicAdd(&nz, local);
  __syncthreads();
  if (threadIdx.x == 0) *flag = (nz == 0) ? 1 : 0;  // 1 => int64 layout
}

__device__ __forceinline__ void edge_at(const int* __restrict__ ew, int E, int e,
                                        int is64, int& s, int& d) {
  if (is64) { s = ew[2 * e]; d = ew[2 * E + 2 * e]; }
  else      { s = ew[e];     d = ew[E + e]; }
}

// ---------------- CSR build ----------------
__global__ void init_deg_kernel(int* deg, int N) {
  int i = blockIdx.x * blockDim.x + threadIdx.x;
  if (i < N) deg[i] = 1;  // self loop
}

__global__ void count_deg_kernel(const int* __restrict__ ew, int E, int* deg,
                                 const int* __restrict__ flag) {
  int is64 = *flag;
  int e = blockIdx.x * blockDim.x + threadIdx.x;
  if (e < E) {
    int s, d;
    edge_at(ew, E, e, is64, s, d);
    atomicAdd(&deg[d], 1);
  }
}

__global__ void scan_kernel(const int* __restrict__ deg, int* rowptr, int* cursor, int N) {
  __shared__ int sums[1024];
  int tid = threadIdx.x;
  int chunk = (N + 1023) >> 10;
  int start = tid * chunk;
  int end = start + chunk; if (end > N) end = N;
  int s = 0;
  for (int i = start; i < end; ++i) s += deg[i];
  sums[tid] = s;
  __syncthreads();
  for (int off = 1; off < 1024; off <<= 1) {
    int v = (tid >= off) ? sums[tid - off] : 0;
    __syncthreads();
    sums[tid] += v;
    __syncthreads();
  }
  int run = (tid == 0) ? 0 : sums[tid - 1];
  for (int i = start; i < end; ++i) {
    rowptr[i] = run; cursor[i] = run;
    run += deg[i];
  }
  if (tid == 1023) rowptr[N] = sums[1023];
}

__global__ void fill_kernel(const int* __restrict__ ew, int E, int N, int* cursor,
                            int* csr, const int* __restrict__ flag) {
  int is64 = *flag;
  int i = blockIdx.x * blockDim.x + threadIdx.x;
  if (i < E) {
    int s, d;
    edge_at(ew, E, i, is64, s, d);
    int pos = atomicAdd(&cursor[d], 1);
    csr[pos] = s;
  } else if (i < E + N) {
    int n = i - E;
    int pos = atomicAdd(&cursor[n], 1);
    csr[pos] = n;
  }
}

// ---------------- input conversions to split-bf16 ----------------
__global__ void convert_x_kernel(const float* __restrict__ x, short* __restrict__ A, int N) {
  int i = blockIdx.x * blockDim.x + threadIdx.x;
  if (i >= N * 256) return;
  int r = i >> 8, c = i & 255;
  float v = x[i];
  unsigned short hi = bf16_of(v);
  unsigned short lo = bf16_of(v - bf16_back(hi));
  A[(ll)r * 512 + c] = (short)hi;
  A[(ll)r * 512 + 256 + c] = (short)lo;
}

// W [K, Nc] fp32 -> Bt [Nc, 3K] bf16: segs [0,K)=W_hi^T, [K,2K)=W_lo^T, [2K,3K)=W_hi^T
__global__ __launch_bounds__(256) void convert_w_kernel(const float* __restrict__ W,
                                                        short* __restrict__ Bt,
                                                        int K, int Nc) {
  __shared__ float t[32][33];
  int k0 = blockIdx.x * 32, n0 = blockIdx.y * 32;
  int r = threadIdx.x >> 3;          // 0..31
  int c4 = (threadIdx.x & 7) * 4;    // 0..28
  float4 v = *(const float4*)&W[(ll)(k0 + r) * Nc + n0 + c4];
  t[r][c4] = v.x; t[r][c4 + 1] = v.y; t[r][c4 + 2] = v.z; t[r][c4 + 3] = v.w;
  __syncthreads();
  int K3 = 3 * K;
  short4 hp, lp;
  float f0 = t[c4 + 0][r], f1 = t[c4 + 1][r], f2 = t[c4 + 2][r], f3 = t[c4 + 3][r];
  unsigned short h0 = bf16_of(f0), h1 = bf16_of(f1), h2 = bf16_of(f2), h3 = bf16_of(f3);
  hp = make_short4((short)h0, (short)h1, (short)h2, (short)h3);
  lp = make_short4((short)bf16_of(f0 - bf16_back(h0)), (short)bf16_of(f1 - bf16_back(h1)),
                   (short)bf16_of(f2 - bf16_back(h2)), (short)bf16_of(f3 - bf16_back(h3)));
  ll base = (ll)(n0 + r) * K3 + k0 + c4;
  *(short4*)&Bt[base] = hp;
  *(short4*)&Bt[base + K] = lp;
  *(short4*)&Bt[base + 2 * K] = hp;
}

// ---------------- MFMA GEMM: C[M,Nc] = A''(split) x Bt^T ----------------
// A: [M, 2K] bf16 ([hi|lo]); Bt: [Nc, 3K] bf16; effective K' = 3K.
// LDS: row-major [128][4 chunks x 16B], chunk slot XOR-rotated per row pair:
//   phys_chunk = log_chunk ^ ((row>>1)&3).
// Staging keeps LDS dst linear (tid*16) and coalesced global reads (lanes
// 0-3 = one 64B row segment, chunk choice XOR-permuted among them).
// Fragment reads apply the same XOR -> 2-way bank aliasing only (free).
template <int HBF16>
__global__ __launch_bounds__(256) void gemm_mfma_kernel(
    const short* __restrict__ A, const short* __restrict__ Bt,
    void* __restrict__ Cv, int M, int Nc, int K) {
  __shared__ char As[8192];
  __shared__ char Bs[8192];
  int tid = threadIdx.x;
  int bm = blockIdx.y * 128, bn = blockIdx.x * 128;
  int lane = tid & 63, wid = tid >> 6;
  int wr = wid >> 1, wc = wid & 1;
  int K2 = 2 * K, K3 = 3 * K;

  f32x4 acc[4][4];
#pragma unroll
  for (int m = 0; m < 4; ++m)
#pragma unroll
    for (int n = 0; n < 4; ++n) acc[m][n] = (f32x4){0.f, 0.f, 0.f, 0.f};

  int srow = tid >> 2;                 // 0..63
  int cphys = tid & 3;                 // LDS chunk slot this thread fills
  int swz = (srow >> 1) & 3;           // same for srow and srow+64
  int clog = (cphys ^ swz) * 8;        // bf16 k-offset actually fetched
  int ra = bm + srow;       if (ra > M - 1) ra = M - 1;
  int rb = bm + srow + 64;  if (rb > M - 1) rb = M - 1;
  const short* aP0 = A + (ll)ra * K2 + clog;
  const short* aP1 = A + (ll)rb * K2 + clog;
  const short* bP0 = Bt + (ll)(bn + srow) * K3 + clog;
  const short* bP1 = Bt + (ll)(bn + srow + 64) * K3 + clog;
  char* asDst = As + tid * 16;
  char* bsDst = Bs + tid * 16;

  int lrow = lane & 15;
  int lchunk = ((lane >> 4) ^ ((lrow >> 1) & 3)) * 16;
  const char* aF0 = As + (wr * 64 + lrow) * 64 + lchunk;
  const char* bF0 = Bs + (wc * 64 + lrow) * 64 + lchunk;

  for (int kt = 0; kt < K3; kt += 32) {
    int akt = kt < K ? kt : kt - K;  // A: hi,hi,lo per segment
    gload16(aP0 + akt, asDst);
    gload16(aP1 + akt, asDst + 4096);
    gload16(bP0 + kt, bsDst);
    gload16(bP1 + kt, bsDst + 4096);
    __syncthreads();
    bf16x8 af[4], bfr[4];
#pragma unroll
    for (int m = 0; m < 4; ++m) af[m] = *(const bf16x8*)(aF0 + m * 1024);
#pragma unroll
    for (int n = 0; n < 4; ++n) bfr[n] = *(const bf16x8*)(bF0 + n * 1024);
#pragma unroll
    for (int m = 0; m < 4; ++m)
#pragma unroll
      for (int n = 0; n < 4; ++n)
        acc[m][n] = __builtin_amdgcn_mfma_f32_16x16x32_bf16(af[m], bfr[n], acc[m][n], 0, 0, 0);
    __syncthreads();
  }

  int crow0 = bm + wr * 64 + (lane >> 4) * 4;
  int ccol0 = bn + wc * 64 + (lane & 15);
#pragma unroll
  for (int m = 0; m < 4; ++m) {
#pragma unroll
    for (int j = 0; j < 4; ++j) {
      int row = crow0 + m * 16 + j;
      if (row < M) {
#pragma unroll
        for (int n = 0; n < 4; ++n) {
          if (HBF16) ((unsigned short*)Cv)[(ll)row * Nc + ccol0 + n * 16] = bf16_of(acc[m][n][j]);
          else       ((float*)Cv)[(ll)row * Nc + ccol0 + n * 16] = acc[m][n][j];
        }
      }
    }
  }
}

// ---------------- per-node attention scores ----------------
template <int HBF16>
__global__ void score_kernel(const void* __restrict__ hv, const float* __restrict__ a_src,
                             const float* __restrict__ a_dst, float* __restrict__ s_src,
                             float* __restrict__ s_dst, int N, int dout) {
  int wid = threadIdx.x >> 6;
  int lane = threadIdx.x & 63;
  int row = blockIdx.x * (blockDim.x >> 6) + wid;
  if (row >= N) return;
  const float4* as4 = (const float4*)a_src;
  const float4* ad4 = (const float4*)a_dst;
  float ss = 0.f, sd = 0.f;
  int nv = dout >> 2;
  if (HBF16) {
    const short4* hr = (const short4*)((const unsigned short*)hv + (ll)row * dout);
    for (int d = lane; d < nv; d += 64) {
      short4 q = hr[d];
      float4 a = as4[d], b = ad4[d];
      float x0 = bf16_back((unsigned short)q.x), x1 = bf16_back((unsigned short)q.y);
      float x2 = bf16_back((unsigned short)q.z), x3 = bf16_back((unsigned short)q.w);
      ss += x0 * a.x + x1 * a.y + x2 * a.z + x3 * a.w;
      sd += x0 * b.x + x1 * b.y + x2 * b.z + x3 * b.w;
    }
  } else {
    const float4* hr = (const float4*)((const float*)hv + (ll)row * dout);
    for (int d = lane; d < nv; d += 64) {
      float4 v = hr[d], a = as4[d], b = ad4[d];
      ss += v.x * a.x + v.y * a.y + v.z * a.z + v.w * a.w;
      sd += v.x * b.x + v.y * b.y + v.z * b.z + v.w * b.w;
    }
  }
#pragma unroll
  for (int o = 32; o > 0; o >>= 1) {
    ss += __shfl_xor(ss, o, 64);
    sd += __shfl_xor(sd, o, 64);
  }
  if (lane == 0) { s_src[row] = ss; s_dst[row] = sd; }
}

// ---------------- segment softmax + weighted aggregation (per node) ----------------
template <int HBF16>
__global__ __launch_bounds__(256) void aggregate_kernel(
    const void* __restrict__ hv, const float* __restrict__ ssrc,
    const float* __restrict__ sdst, const int* __restrict__ rowptr,
    const int* __restrict__ csr, const float* __restrict__ bias,
    float* __restrict__ outF, short* __restrict__ outH, int dout, int do_relu) {
  int node = blockIdx.x;
  int tid = threadIdx.x;
  int lane = tid & 63, wid = tid >> 6;
  int rs = rowptr[node], re = rowptr[node + 1];
  float sd = sdst[node];
  __shared__ float red[4];

  // pass 1: max logit
  float m = -1e30f;
  for (int i = rs + tid; i < re; i += 256) {
    float e = ssrc[csr[i]] + sd;
    e = e > 0.f ? e : NEG_SLOPE * e;
    m = fmaxf(m, e);
  }
#pragma unroll
  for (int o = 32; o > 0; o >>= 1) m = fmaxf(m, __shfl_xor(m, o, 64));
  if (lane == 0) red[wid] = m;
  __syncthreads();
  m = fmaxf(fmaxf(red[0], red[1]), fmaxf(red[2], red[3]));
  __syncthreads();

  // pass 2: denominator
  float den = 0.f;
  for (int i = rs + tid; i < re; i += 256) {
    float e = ssrc[csr[i]] + sd;
    e = e > 0.f ? e : NEG_SLOPE * e;
    den += __expf(e - m);
  }
#pragma unroll
  for (int o = 32; o > 0; o >>= 1) den += __shfl_xor(den, o, 64);
  if (lane == 0) red[wid] = den;
  __syncthreads();
  den = red[0] + red[1] + red[2] + red[3];
  float inv = 1.f / (den + EPS_F);

  // pass 3: weighted accumulate (4 dims per thread)
  int d = tid * 4;
  bool act = d < dout;
  float ax = 0.f, ay = 0.f, az = 0.f, aw = 0.f;
  for (int i = rs; i < re; ++i) {
    int s = csr[i];
    float e = ssrc[s] + sd;
    e = e > 0.f ? e : NEG_SLOPE * e;
    float w = __expf(e - m) * inv;
    if (act) {
      if (HBF16) {
        short4 q = *(const short4*)((const unsigned short*)hv + (ll)s * dout + d);
        ax += w * bf16_back((unsigned short)q.x);
        ay += w * bf16_back((unsigned short)q.y);
        az += w * bf16_back((unsigned short)q.z);
        aw += w * bf16_back((unsigned short)q.w);
      } else {
        float4 hvv = *(const float4*)((const float*)hv + (ll)s * dout + d);
        ax += w * hvv.x; ay += w * hvv.y; az += w * hvv.z; aw += w * hvv.w;
      }
    }
  }
  if (act) {
    float4 bv = *(const float4*)&bias[d];
    float vx = ax + bv.x, vy = ay + bv.y, vz = az + bv.z, vw = aw + bv.w;
    if (do_relu) {
      vx = fmaxf(vx, 0.f); vy = fmaxf(vy, 0.f);
      vz = fmaxf(vz, 0.f); vw = fmaxf(vw, 0.f);
    }
    if (outH) {
      unsigned short h0 = bf16_of(vx), h1 = bf16_of(vy), h2 = bf16_of(vz), h3 = bf16_of(vw);
      short4 hp = make_short4((short)h0, (short)h1, (short)h2, (short)h3);
      short4 lp = make_short4((short)bf16_of(vx - bf16_back(h0)),
                              (short)bf16_of(vy - bf16_back(h1)),
                              (short)bf16_of(vz - bf16_back(h2)),
                              (short)bf16_of(vw - bf16_back(h3)));
      ll base = (ll)node * (2 * dout) + d;
      *(short4*)&outH[base] = hp;
      *(short4*)&outH[base + dout] = lp;
    } else {
      *(float4*)&outF[(ll)node * dout + d] = make_float4(vx, vy, vz, vw);
    }
  }
}

// ---------------- row log_softmax (C == blockDim.x) ----------------
__global__ void log_softmax_kernel(const float* __restrict__ in, float* __restrict__ out,
                                   int C) {
  int row = blockIdx.x;
  int tid = threadIdx.x;
  int lane = tid & 63, wid = tid >> 6;
  __shared__ float red[2];
  float v = in[(ll)row * C + tid];
  float m = v;
#pragma unroll
  for (int o = 32; o > 0; o >>= 1) m = fmaxf(m, __shfl_xor(m, o, 64));
  if (lane == 0) red[wid] = m;
  __syncthreads();
  m = fmaxf(red[0], red[1]);
  __syncthreads();
  float ex = __expf(v - m);
  float s = ex;
#pragma unroll
  for (int o = 32; o > 0; o >>= 1) s += __shfl_xor(s, o, 64);
  if (lane == 0) red[wid] = s;
  __syncthreads();
  s = red[0] + red[1];
  out[(ll)row * C + tid] = v - m - logf(s);
}

// ---------------- launch ----------------
extern "C" void kernel_launch(void* const* d_in, const int* in_sizes, int n_in,
                              void* d_out, int out_size, void* d_ws, size_t ws_size,
                              hipStream_t stream) {
  const float* x = (const float*)d_in[0];
  const int* ew = (const int*)d_in[1];
  int N = in_sizes[0] / 256;
  int E = in_sizes[1] / 2;

  const float* W[4]   = {(const float*)d_in[2],  (const float*)d_in[6],
                         (const float*)d_in[10], (const float*)d_in[14]};
  const float* Asv[4] = {(const float*)d_in[3],  (const float*)d_in[7],
                         (const float*)d_in[11], (const float*)d_in[15]};
  const float* Adv[4] = {(const float*)d_in[4],  (const float*)d_in[8],
                         (const float*)d_in[12], (const float*)d_in[16]};
  const float* Bv[4]  = {(const float*)d_in[5],  (const float*)d_in[9],
                         (const float*)d_in[13], (const float*)d_in[17]};
  const int din[4]  = {256, 1024, 1024, 512};
  const int dout[4] = {1024, 1024, 512, 128};

  char* ws = (char*)d_ws;
  size_t off = 0;
  auto alloc = [&](size_t bytes) {
    void* p = ws + off;
    off += (bytes + 255) & ~(size_t)255;
    return p;
  };
  unsigned short* hB = (unsigned short*)alloc((size_t)N * 1024 * 2);  // bf16 h (layers 1-3)
  float* hF   = (float*)alloc((size_t)N * 128 * 4);                   // fp32 h (layer 4)
  short* bufP = (short*)alloc((size_t)N * 2048 * 2);
  short* bufQ = (short*)alloc((size_t)N * 2048 * 2);
  float* sF   = (float*)alloc((size_t)N * 128 * 4);
  float* s_src = (float*)alloc((size_t)N * 4);
  float* s_dst = (float*)alloc((size_t)N * 4);
  int* deg    = (int*)alloc((size_t)(N + 1) * 4);
  int* rowptr = (int*)alloc((size_t)(N + 1) * 4);
  int* cursor = (int*)alloc((size_t)(N + 1) * 4);
  int* csr    = (int*)alloc((size_t)(E + N) * 4);
  int* flag   = (int*)alloc(256);
  short* Bt[4];
  for (int l = 0; l < 4; ++l) Bt[l] = (short*)alloc((size_t)dout[l] * 3 * din[l] * 2);

  detect_int64_kernel<<<1, 256, 0, stream>>>((const unsigned int*)ew, E, flag);
  init_deg_kernel<<<(N + 255) / 256, 256, 0, stream>>>(deg, N);
  count_deg_kernel<<<(E + 255) / 256, 256, 0, stream>>>(ew, E, deg, flag);
  scan_kernel<<<1, 1024, 0, stream>>>(deg, rowptr, cursor, N);
  fill_kernel<<<(E + N + 255) / 256, 256, 0, stream>>>(ew, E, N, cursor, csr, flag);

  convert_x_kernel<<<(N * 256 + 255) / 256, 256, 0, stream>>>(x, bufP, N);
  for (int l = 0; l < 4; ++l) {
    dim3 cg(din[l] / 32, dout[l] / 32);
    convert_w_kernel<<<cg, 256, 0, stream>>>(W[l], Bt[l], din[l], dout[l]);
  }

  short* cur = bufP;
  short* nxt = bufQ;
  for (int l = 0; l < 4; ++l) {
    dim3 ggrid(dout[l] / 128, (N + 127) / 128);
    if (l < 3) {
      gemm_mfma_kernel<1><<<ggrid, 256, 0, stream>>>(cur, Bt[l], hB, N, dout[l], din[l]);
      score_kernel<1><<<(N + 3) / 4, 256, 0, stream>>>(hB, Asv[l], Adv[l], s_src, s_dst,
                                                       N, dout[l]);
      aggregate_kernel<1><<<N, 256, 0, stream>>>(hB, s_src, s_dst, rowptr, csr, Bv[l],
                                                 nullptr, nxt, dout[l], 1);
    } else {
      gemm_mfma_kernel<0><<<ggrid, 256, 0, stream>>>(cur, Bt[l], hF, N, dout[l], din[l]);
      score_kernel<0><<<(N + 3) / 4, 256, 0, stream>>>(hF, Asv[l], Adv[l], s_src, s_dst,
                                                       N, dout[l]);
      aggregate_kernel<0><<<N, 256, 0, stream>>>(hF, s_src, s_dst, rowptr, csr, Bv[l],
                                                 sF, nullptr, dout[l], 0);
    }
    short* t = cur; cur = nxt; nxt = t;
  }
  log_softmax_kernel<<<N, 128, 0, stream>>>(sF, (float*)d_out, 128);
}

// Round 5
// 401.561 us; speedup vs baseline: 1.6461x; 1.3021x over previous
//
#include <hip/hip_runtime.h>
#include <math.h>

#define NEG_SLOPE 0.2f
#define EPS_F 1e-16f
typedef long long ll;

typedef __attribute__((ext_vector_type(4))) float f32x4;
typedef __attribute__((ext_vector_type(8))) short bf16x8;

// ---------------- bf16 helpers (bit-level, RTN-even) ----------------
__device__ __forceinline__ unsigned short bf16_of(float f) {
  unsigned u = __float_as_uint(f);
  u += 0x7fffu + ((u >> 16) & 1u);
  return (unsigned short)(u >> 16);
}
__device__ __forceinline__ float bf16_back(unsigned short s) {
  return __uint_as_float((unsigned)s << 16);
}

__device__ __forceinline__ void gload16(const void* g, void* l) {
  __builtin_amdgcn_global_load_lds((const __attribute__((address_space(1))) void*)g,
                                   (__attribute__((address_space(3))) void*)l, 16, 0, 0);
}

// ---------------- edge dtype detection (int64 vs int32) ----------------
__global__ void detect_int64_kernel(const unsigned int* __restrict__ w, int E,
                                    int* __restrict__ flag) {
  __shared__ int nz;
  if (threadIdx.x == 0) nz = 0;
  __syncthreads();
  int cnt = E < 2048 ? E : 2048;
  int local = 0;
  for (int i = threadIdx.x; i < cnt; i += blockDim.x)
    if (w[2 * i + 1] != 0u) local++;
  if (local) atomicAdd(&nz, local);
  __syncthreads();
  if (threadIdx.x == 0) *flag = (nz == 0) ? 1 : 0;  // 1 => int64 layout
}

__device__ __forceinline__ void edge_at(const int* __restrict__ ew, int E, int e,
                                        int is64, int& s, int& d) {
  if (is64) { s = ew[2 * e]; d = ew[2 * E + 2 * e]; }
  else      { s = ew[e];     d = ew[E + e]; }
}

// ---------------- CSR build ----------------
__global__ void init_deg_kernel(int* deg, int N) {
  int i = blockIdx.x * blockDim.x + threadIdx.x;
  if (i < N) deg[i] = 1;  // self loop
}

__global__ void count_deg_kernel(const int* __restrict__ ew, int E, int* deg,
                                 const int* __restrict__ flag) {
  int is64 = *flag;
  int e = blockIdx.x * blockDim.x + threadIdx.x;
  if (e < E) {
    int s, d;
    edge_at(ew, E, e, is64, s, d);
    atomicAdd(&deg[d], 1);
  }
}

__global__ void scan_kernel(const int* __restrict__ deg, int* rowptr, int* cursor, int N) {
  __shared__ int sums[1024];
  int tid = threadIdx.x;
  int chunk = (N + 1023) >> 10;
  int start = tid * chunk;
  int end = start + chunk; if (end > N) end = N;
  int s = 0;
  for (int i = start; i < end; ++i) s += deg[i];
  sums[tid] = s;
  __syncthreads();
  for (int off = 1; off < 1024; off <<= 1) {
    int v = (tid >= off) ? sums[tid - off] : 0;
    __syncthreads();
    sums[tid] += v;
    __syncthreads();
  }
  int run = (tid == 0) ? 0 : sums[tid - 1];
  for (int i = start; i < end; ++i) {
    rowptr[i] = run; cursor[i] = run;
    run += deg[i];
  }
  if (tid == 1023) rowptr[N] = sums[1023];
}

__global__ void fill_kernel(const int* __restrict__ ew, int E, int N, int* cursor,
                            int* csr, const int* __restrict__ flag) {
  int is64 = *flag;
  int i = blockIdx.x * blockDim.x + threadIdx.x;
  if (i < E) {
    int s, d;
    edge_at(ew, E, i, is64, s, d);
    int pos = atomicAdd(&cursor[d], 1);
    csr[pos] = s;
  } else if (i < E + N) {
    int n = i - E;
    int pos = atomicAdd(&cursor[n], 1);
    csr[pos] = n;
  }
}

// ---------------- input conversions to split-bf16 ----------------
__global__ void convert_x_kernel(const float* __restrict__ x, short* __restrict__ A, int N) {
  int i = blockIdx.x * blockDim.x + threadIdx.x;
  if (i >= N * 256) return;
  int r = i >> 8, c = i & 255;
  float v = x[i];
  unsigned short hi = bf16_of(v);
  unsigned short lo = bf16_of(v - bf16_back(hi));
  A[(ll)r * 512 + c] = (short)hi;
  A[(ll)r * 512 + 256 + c] = (short)lo;
}

// W [K, Nc] fp32 -> Bt [Nc, K] bf16 (W_hi^T only)
__global__ __launch_bounds__(256) void convert_w_kernel(const float* __restrict__ W,
                                                        short* __restrict__ Bt,
                                                        int K, int Nc) {
  __shared__ float t[32][33];
  int k0 = blockIdx.x * 32, n0 = blockIdx.y * 32;
  int r = threadIdx.x >> 3;          // 0..31
  int c4 = (threadIdx.x & 7) * 4;    // 0..28
  float4 v = *(const float4*)&W[(ll)(k0 + r) * Nc + n0 + c4];
  t[r][c4] = v.x; t[r][c4 + 1] = v.y; t[r][c4 + 2] = v.z; t[r][c4 + 3] = v.w;
  __syncthreads();
  float f0 = t[c4 + 0][r], f1 = t[c4 + 1][r], f2 = t[c4 + 2][r], f3 = t[c4 + 3][r];
  short4 hp = make_short4((short)bf16_of(f0), (short)bf16_of(f1),
                          (short)bf16_of(f2), (short)bf16_of(f3));
  *(short4*)&Bt[(ll)(n0 + r) * K + k0 + c4] = hp;
}

// ---------------- MFMA GEMM: C[M,Nc] = (A_hi + A_lo) x W_hi ----------------
// A: [M, 2K] bf16 ([hi|lo]); Bt: [Nc, K] bf16 (W_hi^T).
// Per K-step stage {A_hi, A_lo, B} tiles (128x32 each), 32 MFMA/step.
// LDS per tile: row-major [128][4 chunks x 16B], chunk XOR-rotated per row
// pair (phys = log ^ ((row>>1)&3)); staging keeps LDS dst linear and global
// reads coalesced (4 lanes cover one 64B row window, chunk choice permuted).
// XCD-chunked bijective block swizzle (m204) for A-panel L2 reuse.
template <int HBF16>
__global__ __launch_bounds__(256) void gemm_mfma_kernel(
    const short* __restrict__ A, const short* __restrict__ Bt,
    void* __restrict__ Cv, int M, int Nc, int K) {
  __shared__ char Ah[8192];
  __shared__ char Al[8192];
  __shared__ char Bs[8192];
  int tid = threadIdx.x;

  int nwg = gridDim.x * gridDim.y;
  int hb = blockIdx.y * gridDim.x + blockIdx.x;
  int xcd = hb & 7, q = nwg >> 3, r = nwg & 7;
  int lg = (xcd < r ? xcd * (q + 1) : r * (q + 1) + (xcd - r) * q) + (hb >> 3);
  int bx = lg % gridDim.x, by = lg / gridDim.x;
  int bm = by * 128, bn = bx * 128;

  int lane = tid & 63, wid = tid >> 6;
  int wr = wid >> 1, wc = wid & 1;
  int K2 = 2 * K;

  f32x4 acc[4][4];
#pragma unroll
  for (int m = 0; m < 4; ++m)
#pragma unroll
    for (int n = 0; n < 4; ++n) acc[m][n] = (f32x4){0.f, 0.f, 0.f, 0.f};

  int srow = tid >> 2;                 // 0..63
  int cphys = tid & 3;                 // LDS chunk slot this thread fills
  int swz = (srow >> 1) & 3;
  int clog = (cphys ^ swz) * 8;        // bf16 k-offset actually fetched
  int ra = bm + srow;       if (ra > M - 1) ra = M - 1;
  int rb = bm + srow + 64;  if (rb > M - 1) rb = M - 1;
  const short* aP0 = A + (ll)ra * K2 + clog;
  const short* aP1 = A + (ll)rb * K2 + clog;
  const short* bP0 = Bt + (ll)(bn + srow) * K + clog;
  const short* bP1 = Bt + (ll)(bn + srow + 64) * K + clog;
  char* dst = (char*)nullptr;
  int dstOff = tid * 16;

  int lrow = lane & 15;
  int lchunk = ((lane >> 4) ^ ((lrow >> 1) & 3)) * 16;
  int fOffA = (wr * 64 + lrow) * 64 + lchunk;
  int fOffB = (wc * 64 + lrow) * 64 + lchunk;

  for (int kt = 0; kt < K; kt += 32) {
    gload16(aP0 + kt, Ah + dstOff);
    gload16(aP1 + kt, Ah + 4096 + dstOff);
    gload16(aP0 + K + kt, Al + dstOff);
    gload16(aP1 + K + kt, Al + 4096 + dstOff);
    gload16(bP0 + kt, Bs + dstOff);
    gload16(bP1 + kt, Bs + 4096 + dstOff);
    __syncthreads();
    bf16x8 ah[4], al[4], bfr[4];
#pragma unroll
    for (int m = 0; m < 4; ++m) {
      ah[m] = *(const bf16x8*)(Ah + fOffA + m * 1024);
      al[m] = *(const bf16x8*)(Al + fOffA + m * 1024);
    }
#pragma unroll
    for (int n = 0; n < 4; ++n) bfr[n] = *(const bf16x8*)(Bs + fOffB + n * 1024);
#pragma unroll
    for (int m = 0; m < 4; ++m)
#pragma unroll
      for (int n = 0; n < 4; ++n) {
        acc[m][n] = __builtin_amdgcn_mfma_f32_16x16x32_bf16(ah[m], bfr[n], acc[m][n], 0, 0, 0);
        acc[m][n] = __builtin_amdgcn_mfma_f32_16x16x32_bf16(al[m], bfr[n], acc[m][n], 0, 0, 0);
      }
    __syncthreads();
  }
  (void)dst;

  int crow0 = bm + wr * 64 + (lane >> 4) * 4;
  int ccol0 = bn + wc * 64 + (lane & 15);
#pragma unroll
  for (int m = 0; m < 4; ++m) {
#pragma unroll
    for (int j = 0; j < 4; ++j) {
      int row = crow0 + m * 16 + j;
      if (row < M) {
#pragma unroll
        for (int n = 0; n < 4; ++n) {
          if (HBF16) ((unsigned short*)Cv)[(ll)row * Nc + ccol0 + n * 16] = bf16_of(acc[m][n][j]);
          else       ((float*)Cv)[(ll)row * Nc + ccol0 + n * 16] = acc[m][n][j];
        }
      }
    }
  }
}

// ---------------- per-node attention scores ----------------
template <int HBF16>
__global__ void score_kernel(const void* __restrict__ hv, const float* __restrict__ a_src,
                             const float* __restrict__ a_dst, float* __restrict__ s_src,
                             float* __restrict__ s_dst, int N, int dout) {
  int wid = threadIdx.x >> 6;
  int lane = threadIdx.x & 63;
  int row = blockIdx.x * (blockDim.x >> 6) + wid;
  if (row >= N) return;
  const float4* as4 = (const float4*)a_src;
  const float4* ad4 = (const float4*)a_dst;
  float ss = 0.f, sd = 0.f;
  int nv = dout >> 2;
  if (HBF16) {
    const short4* hr = (const short4*)((const unsigned short*)hv + (ll)row * dout);
    for (int d = lane; d < nv; d += 64) {
      short4 q = hr[d];
      float4 a = as4[d], b = ad4[d];
      float x0 = bf16_back((unsigned short)q.x), x1 = bf16_back((unsigned short)q.y);
      float x2 = bf16_back((unsigned short)q.z), x3 = bf16_back((unsigned short)q.w);
      ss += x0 * a.x + x1 * a.y + x2 * a.z + x3 * a.w;
      sd += x0 * b.x + x1 * b.y + x2 * b.z + x3 * b.w;
    }
  } else {
    const float4* hr = (const float4*)((const float*)hv + (ll)row * dout);
    for (int d = lane; d < nv; d += 64) {
      float4 v = hr[d], a = as4[d], b = ad4[d];
      ss += v.x * a.x + v.y * a.y + v.z * a.z + v.w * a.w;
      sd += v.x * b.x + v.y * b.y + v.z * b.z + v.w * b.w;
    }
  }
#pragma unroll
  for (int o = 32; o > 0; o >>= 1) {
    ss += __shfl_xor(ss, o, 64);
    sd += __shfl_xor(sd, o, 64);
  }
  if (lane == 0) { s_src[row] = ss; s_dst[row] = sd; }
}

// ---------------- segment softmax + weighted aggregation (per node) ----------------
template <int HBF16>
__global__ __launch_bounds__(256) void aggregate_kernel(
    const void* __restrict__ hv, const float* __restrict__ ssrc,
    const float* __restrict__ sdst, const int* __restrict__ rowptr,
    const int* __restrict__ csr, const float* __restrict__ bias,
    float* __restrict__ outF, short* __restrict__ outH, int dout, int do_relu) {
  int node = blockIdx.x;
  int tid = threadIdx.x;
  int lane = tid & 63, wid = tid >> 6;
  int rs = rowptr[node], re = rowptr[node + 1];
  float sd = sdst[node];
  __shared__ float red[4];

  // pass 1: max logit
  float m = -1e30f;
  for (int i = rs + tid; i < re; i += 256) {
    float e = ssrc[csr[i]] + sd;
    e = e > 0.f ? e : NEG_SLOPE * e;
    m = fmaxf(m, e);
  }
#pragma unroll
  for (int o = 32; o > 0; o >>= 1) m = fmaxf(m, __shfl_xor(m, o, 64));
  if (lane == 0) red[wid] = m;
  __syncthreads();
  m = fmaxf(fmaxf(red[0], red[1]), fmaxf(red[2], red[3]));
  __syncthreads();

  // pass 2: denominator
  float den = 0.f;
  for (int i = rs + tid; i < re; i += 256) {
    float e = ssrc[csr[i]] + sd;
    e = e > 0.f ? e : NEG_SLOPE * e;
    den += __expf(e - m);
  }
#pragma unroll
  for (int o = 32; o > 0; o >>= 1) den += __shfl_xor(den, o, 64);
  if (lane == 0) red[wid] = den;
  __syncthreads();
  den = red[0] + red[1] + red[2] + red[3];
  float inv = 1.f / (den + EPS_F);

  // pass 3: weighted accumulate (4 dims per thread)
  int d = tid * 4;
  bool act = d < dout;
  float ax = 0.f, ay = 0.f, az = 0.f, aw = 0.f;
  for (int i = rs; i < re; ++i) {
    int s = csr[i];
    float e = ssrc[s] + sd;
    e = e > 0.f ? e : NEG_SLOPE * e;
    float w = __expf(e - m) * inv;
    if (act) {
      if (HBF16) {
        short4 q = *(const short4*)((const unsigned short*)hv + (ll)s * dout + d);
        ax += w * bf16_back((unsigned short)q.x);
        ay += w * bf16_back((unsigned short)q.y);
        az += w * bf16_back((unsigned short)q.z);
        aw += w * bf16_back((unsigned short)q.w);
      } else {
        float4 hvv = *(const float4*)((const float*)hv + (ll)s * dout + d);
        ax += w * hvv.x; ay += w * hvv.y; az += w * hvv.z; aw += w * hvv.w;
      }
    }
  }
  if (act) {
    float4 bv = *(const float4*)&bias[d];
    float vx = ax + bv.x, vy = ay + bv.y, vz = az + bv.z, vw = aw + bv.w;
    if (do_relu) {
      vx = fmaxf(vx, 0.f); vy = fmaxf(vy, 0.f);
      vz = fmaxf(vz, 0.f); vw = fmaxf(vw, 0.f);
    }
    if (outH) {
      unsigned short h0 = bf16_of(vx), h1 = bf16_of(vy), h2 = bf16_of(vz), h3 = bf16_of(vw);
      short4 hp = make_short4((short)h0, (short)h1, (short)h2, (short)h3);
      short4 lp = make_short4((short)bf16_of(vx - bf16_back(h0)),
                              (short)bf16_of(vy - bf16_back(h1)),
                              (short)bf16_of(vz - bf16_back(h2)),
                              (short)bf16_of(vw - bf16_back(h3)));
      ll base = (ll)node * (2 * dout) + d;
      *(short4*)&outH[base] = hp;
      *(short4*)&outH[base + dout] = lp;
    } else {
      *(float4*)&outF[(ll)node * dout + d] = make_float4(vx, vy, vz, vw);
    }
  }
}

// ---------------- row log_softmax (C == blockDim.x) ----------------
__global__ void log_softmax_kernel(const float* __restrict__ in, float* __restrict__ out,
                                   int C) {
  int row = blockIdx.x;
  int tid = threadIdx.x;
  int lane = tid & 63, wid = tid >> 6;
  __shared__ float red[2];
  float v = in[(ll)row * C + tid];
  float m = v;
#pragma unroll
  for (int o = 32; o > 0; o >>= 1) m = fmaxf(m, __shfl_xor(m, o, 64));
  if (lane == 0) red[wid] = m;
  __syncthreads();
  m = fmaxf(red[0], red[1]);
  __syncthreads();
  float ex = __expf(v - m);
  float s = ex;
#pragma unroll
  for (int o = 32; o > 0; o >>= 1) s += __shfl_xor(s, o, 64);
  if (lane == 0) red[wid] = s;
  __syncthreads();
  s = red[0] + red[1];
  out[(ll)row * C + tid] = v - m - logf(s);
}

// ---------------- launch ----------------
extern "C" void kernel_launch(void* const* d_in, const int* in_sizes, int n_in,
                              void* d_out, int out_size, void* d_ws, size_t ws_size,
                              hipStream_t stream) {
  const float* x = (const float*)d_in[0];
  const int* ew = (const int*)d_in[1];
  int N = in_sizes[0] / 256;
  int E = in_sizes[1] / 2;

  const float* W[4]   = {(const float*)d_in[2],  (const float*)d_in[6],
                         (const float*)d_in[10], (const float*)d_in[14]};
  const float* Asv[4] = {(const float*)d_in[3],  (const float*)d_in[7],
                         (const float*)d_in[11], (const float*)d_in[15]};
  const float* Adv[4] = {(const float*)d_in[4],  (const float*)d_in[8],
                         (const float*)d_in[12], (const float*)d_in[16]};
  const float* Bv[4]  = {(const float*)d_in[5],  (const float*)d_in[9],
                         (const float*)d_in[13], (const float*)d_in[17]};
  const int din[4]  = {256, 1024, 1024, 512};
  const int dout[4] = {1024, 1024, 512, 128};

  char* ws = (char*)d_ws;
  size_t off = 0;
  auto alloc = [&](size_t bytes) {
    void* p = ws + off;
    off += (bytes + 255) & ~(size_t)255;
    return p;
  };
  unsigned short* hB = (unsigned short*)alloc((size_t)N * 1024 * 2);  // bf16 h (layers 1-3)
  float* hF   = (float*)alloc((size_t)N * 128 * 4);                   // fp32 h (layer 4)
  short* bufP = (short*)alloc((size_t)N * 2048 * 2);
  short* bufQ = (short*)alloc((size_t)N * 2048 * 2);
  float* sF   = (float*)alloc((size_t)N * 128 * 4);
  float* s_src = (float*)alloc((size_t)N * 4);
  float* s_dst = (float*)alloc((size_t)N * 4);
  int* deg    = (int*)alloc((size_t)(N + 1) * 4);
  int* rowptr = (int*)alloc((size_t)(N + 1) * 4);
  int* cursor = (int*)alloc((size_t)(N + 1) * 4);
  int* csr    = (int*)alloc((size_t)(E + N) * 4);
  int* flag   = (int*)alloc(256);
  short* Bt[4];
  for (int l = 0; l < 4; ++l) Bt[l] = (short*)alloc((size_t)dout[l] * din[l] * 2);

  detect_int64_kernel<<<1, 256, 0, stream>>>((const unsigned int*)ew, E, flag);
  init_deg_kernel<<<(N + 255) / 256, 256, 0, stream>>>(deg, N);
  count_deg_kernel<<<(E + 255) / 256, 256, 0, stream>>>(ew, E, deg, flag);
  scan_kernel<<<1, 1024, 0, stream>>>(deg, rowptr, cursor, N);
  fill_kernel<<<(E + N + 255) / 256, 256, 0, stream>>>(ew, E, N, cursor, csr, flag);

  convert_x_kernel<<<(N * 256 + 255) / 256, 256, 0, stream>>>(x, bufP, N);
  for (int l = 0; l < 4; ++l) {
    dim3 cg(din[l] / 32, dout[l] / 32);
    convert_w_kernel<<<cg, 256, 0, stream>>>(W[l], Bt[l], din[l], dout[l]);
  }

  short* cur = bufP;
  short* nxt = bufQ;
  for (int l = 0; l < 4; ++l) {
    dim3 ggrid(dout[l] / 128, (N + 127) / 128);
    if (l < 3) {
      gemm_mfma_kernel<1><<<ggrid, 256, 0, stream>>>(cur, Bt[l], hB, N, dout[l], din[l]);
      score_kernel<1><<<(N + 3) / 4, 256, 0, stream>>>(hB, Asv[l], Adv[l], s_src, s_dst,
                                                       N, dout[l]);
      aggregate_kernel<1><<<N, 256, 0, stream>>>(hB, s_src, s_dst, rowptr, csr, Bv[l],
                                                 nullptr, nxt, dout[l], 1);
    } else {
      gemm_mfma_kernel<0><<<ggrid, 256, 0, stream>>>(cur, Bt[l], hF, N, dout[l], din[l]);
      score_kernel<0><<<(N + 3) / 4, 256, 0, stream>>>(hF, Asv[l], Adv[l], s_src, s_dst,
                                                       N, dout[l]);
      aggregate_kernel<0><<<N, 256, 0, stream>>>(hF, s_src, s_dst, rowptr, csr, Bv[l],
                                                 sF, nullptr, dout[l], 0);
    }
    short* t = cur; cur = nxt; nxt = t;
  }
  log_softmax_kernel<<<N, 128, 0, stream>>>(sF, (float*)d_out, 128);
}

// Round 6
// 372.644 us; speedup vs baseline: 1.7739x; 1.0776x over previous
//
#include <hip/hip_runtime.h>
#include <math.h>

#define NEG_SLOPE 0.2f
#define EPS_F 1e-16f
#define MAXD 512
typedef long long ll;

typedef __attribute__((ext_vector_type(4))) float f32x4;
typedef __attribute__((ext_vector_type(8))) short bf16x8;

// ---------------- bf16 helpers (bit-level, RTN-even) ----------------
__device__ __forceinline__ unsigned short bf16_of(float f) {
  unsigned u = __float_as_uint(f);
  u += 0x7fffu + ((u >> 16) & 1u);
  return (unsigned short)(u >> 16);
}
__device__ __forceinline__ float bf16_back(unsigned short s) {
  return __uint_as_float((unsigned)s << 16);
}

__device__ __forceinline__ void gload16(const void* g, void* l) {
  __builtin_amdgcn_global_load_lds((const __attribute__((address_space(1))) void*)g,
                                   (__attribute__((address_space(3))) void*)l, 16, 0, 0);
}

// ---------------- edge dtype detection (int64 vs int32) ----------------
__global__ void detect_int64_kernel(const unsigned int* __restrict__ w, int E,
                                    int* __restrict__ flag) {
  __shared__ int nz;
  if (threadIdx.x == 0) nz = 0;
  __syncthreads();
  int cnt = E < 2048 ? E : 2048;
  int local = 0;
  for (int i = threadIdx.x; i < cnt; i += blockDim.x)
    if (w[2 * i + 1] != 0u) local++;
  if (local) atomicAdd(&nz, local);
  __syncthreads();
  if (threadIdx.x == 0) *flag = (nz == 0) ? 1 : 0;  // 1 => int64 layout
}

__device__ __forceinline__ void edge_at(const int* __restrict__ ew, int E, int e,
                                        int is64, int& s, int& d) {
  if (is64) { s = ew[2 * e]; d = ew[2 * E + 2 * e]; }
  else      { s = ew[e];     d = ew[E + e]; }
}

// ---------------- CSR build ----------------
__global__ void init_deg_kernel(int* deg, int N) {
  int i = blockIdx.x * blockDim.x + threadIdx.x;
  if (i < N) deg[i] = 1;  // self loop
}

__global__ void count_deg_kernel(const int* __restrict__ ew, int E, int* deg,
                                 const int* __restrict__ flag) {
  int is64 = *flag;
  int e = blockIdx.x * blockDim.x + threadIdx.x;
  if (e < E) {
    int s, d;
    edge_at(ew, E, e, is64, s, d);
    atomicAdd(&deg[d], 1);
  }
}

__global__ void scan_kernel(const int* __restrict__ deg, int* rowptr, int* cursor, int N) {
  __shared__ int sums[1024];
  int tid = threadIdx.x;
  int chunk = (N + 1023) >> 10;
  int start = tid * chunk;
  int end = start + chunk; if (end > N) end = N;
  int s = 0;
  for (int i = start; i < end; ++i) s += deg[i];
  sums[tid] = s;
  __syncthreads();
  for (int off = 1; off < 1024; off <<= 1) {
    int v = (tid >= off) ? sums[tid - off] : 0;
    __syncthreads();
    sums[tid] += v;
    __syncthreads();
  }
  int run = (tid == 0) ? 0 : sums[tid - 1];
  for (int i = start; i < end; ++i) {
    rowptr[i] = run; cursor[i] = run;
    run += deg[i];
  }
  if (tid == 1023) rowptr[N] = sums[1023];
}

__global__ void fill_kernel(const int* __restrict__ ew, int E, int N, int* cursor,
                            int* csr, const int* __restrict__ flag) {
  int is64 = *flag;
  int i = blockIdx.x * blockDim.x + threadIdx.x;
  if (i < E) {
    int s, d;
    edge_at(ew, E, i, is64, s, d);
    int pos = atomicAdd(&cursor[d], 1);
    csr[pos] = s;
  } else if (i < E + N) {
    int n = i - E;
    int pos = atomicAdd(&cursor[n], 1);
    csr[pos] = n;
  }
}

// ---------------- input conversions to split-bf16 ----------------
__global__ void convert_x_kernel(const float* __restrict__ x, short* __restrict__ A, int N) {
  int i = blockIdx.x * blockDim.x + threadIdx.x;
  if (i >= N * 256) return;
  int r = i >> 8, c = i & 255;
  float v = x[i];
  unsigned short hi = bf16_of(v);
  unsigned short lo = bf16_of(v - bf16_back(hi));
  A[(ll)r * 512 + c] = (short)hi;
  A[(ll)r * 512 + 256 + c] = (short)lo;
}

// W [K, Nc] fp32 -> Bt [Nc, K] bf16 (W_hi^T only)
__global__ __launch_bounds__(256) void convert_w_kernel(const float* __restrict__ W,
                                                        short* __restrict__ Bt,
                                                        int K, int Nc) {
  __shared__ float t[32][33];
  int k0 = blockIdx.x * 32, n0 = blockIdx.y * 32;
  int r = threadIdx.x >> 3;          // 0..31
  int c4 = (threadIdx.x & 7) * 4;    // 0..28
  float4 v = *(const float4*)&W[(ll)(k0 + r) * Nc + n0 + c4];
  t[r][c4] = v.x; t[r][c4 + 1] = v.y; t[r][c4 + 2] = v.z; t[r][c4 + 3] = v.w;
  __syncthreads();
  float f0 = t[c4 + 0][r], f1 = t[c4 + 1][r], f2 = t[c4 + 2][r], f3 = t[c4 + 3][r];
  short4 hp = make_short4((short)bf16_of(f0), (short)bf16_of(f1),
                          (short)bf16_of(f2), (short)bf16_of(f3));
  *(short4*)&Bt[(ll)(n0 + r) * K + k0 + c4] = hp;
}

// ---------------- MFMA GEMM: C[M,Nc] = (A_hi + A_lo) x W_hi, fused scores ----
// A: [M, 2K] bf16 ([hi|lo]); Bt: [Nc, K] bf16 (W_hi^T).
// Per K-step stage {A_hi, A_lo, B} (128x32 each), 32 MFMA/step.
// LDS: row-major [128][4 x 16B], chunk XOR-rotated per row pair; XCD-chunked
// bijective block swizzle. Epilogue computes per-row partial dots with
// a_src/a_dst (16-lane shfl reduce, plain store per (col-block,wc) partial).
template <int HBF16>
__global__ __launch_bounds__(256) void gemm_mfma_kernel(
    const short* __restrict__ A, const short* __restrict__ Bt,
    void* __restrict__ Cv, const float* __restrict__ a_src,
    const float* __restrict__ a_dst, float* __restrict__ partS,
    float* __restrict__ partD, int M, int Nc, int K) {
  __shared__ char Ah[8192];
  __shared__ char Al[8192];
  __shared__ char Bs[8192];
  int tid = threadIdx.x;

  int nwg = gridDim.x * gridDim.y;
  int hb = blockIdx.y * gridDim.x + blockIdx.x;
  int xcd = hb & 7, q = nwg >> 3, r = nwg & 7;
  int lg = (xcd < r ? xcd * (q + 1) : r * (q + 1) + (xcd - r) * q) + (hb >> 3);
  int bx = lg % gridDim.x, by = lg / gridDim.x;
  int bm = by * 128, bn = bx * 128;

  int lane = tid & 63, wid = tid >> 6;
  int wr = wid >> 1, wc = wid & 1;
  int K2 = 2 * K;

  f32x4 acc[4][4];
#pragma unroll
  for (int m = 0; m < 4; ++m)
#pragma unroll
    for (int n = 0; n < 4; ++n) acc[m][n] = (f32x4){0.f, 0.f, 0.f, 0.f};

  int srow = tid >> 2;                 // 0..63
  int cphys = tid & 3;                 // LDS chunk slot this thread fills
  int swz = (srow >> 1) & 3;
  int clog = (cphys ^ swz) * 8;        // bf16 k-offset actually fetched
  int ra = bm + srow;       if (ra > M - 1) ra = M - 1;
  int rb = bm + srow + 64;  if (rb > M - 1) rb = M - 1;
  const short* aP0 = A + (ll)ra * K2 + clog;
  const short* aP1 = A + (ll)rb * K2 + clog;
  const short* bP0 = Bt + (ll)(bn + srow) * K + clog;
  const short* bP1 = Bt + (ll)(bn + srow + 64) * K + clog;
  int dstOff = tid * 16;

  int lrow = lane & 15;
  int lchunk = ((lane >> 4) ^ ((lrow >> 1) & 3)) * 16;
  int fOffA = (wr * 64 + lrow) * 64 + lchunk;
  int fOffB = (wc * 64 + lrow) * 64 + lchunk;

  for (int kt = 0; kt < K; kt += 32) {
    gload16(aP0 + kt, Ah + dstOff);
    gload16(aP1 + kt, Ah + 4096 + dstOff);
    gload16(aP0 + K + kt, Al + dstOff);
    gload16(aP1 + K + kt, Al + 4096 + dstOff);
    gload16(bP0 + kt, Bs + dstOff);
    gload16(bP1 + kt, Bs + 4096 + dstOff);
    __syncthreads();
    bf16x8 ah[4], al[4], bfr[4];
#pragma unroll
    for (int m = 0; m < 4; ++m) {
      ah[m] = *(const bf16x8*)(Ah + fOffA + m * 1024);
      al[m] = *(const bf16x8*)(Al + fOffA + m * 1024);
    }
#pragma unroll
    for (int n = 0; n < 4; ++n) bfr[n] = *(const bf16x8*)(Bs + fOffB + n * 1024);
#pragma unroll
    for (int m = 0; m < 4; ++m)
#pragma unroll
      for (int n = 0; n < 4; ++n) {
        acc[m][n] = __builtin_amdgcn_mfma_f32_16x16x32_bf16(ah[m], bfr[n], acc[m][n], 0, 0, 0);
        acc[m][n] = __builtin_amdgcn_mfma_f32_16x16x32_bf16(al[m], bfr[n], acc[m][n], 0, 0, 0);
      }
    __syncthreads();
  }

  int crow0 = bm + wr * 64 + (lane >> 4) * 4;
  int ccol0 = bn + wc * 64 + (lane & 15);
#pragma unroll
  for (int m = 0; m < 4; ++m) {
#pragma unroll
    for (int j = 0; j < 4; ++j) {
      int row = crow0 + m * 16 + j;
      if (row < M) {
#pragma unroll
        for (int n = 0; n < 4; ++n) {
          if (HBF16) ((unsigned short*)Cv)[(ll)row * Nc + ccol0 + n * 16] = bf16_of(acc[m][n][j]);
          else       ((float*)Cv)[(ll)row * Nc + ccol0 + n * 16] = acc[m][n][j];
        }
      }
    }
  }

  // fused partial attention scores
  float as4[4], ad4[4];
#pragma unroll
  for (int n = 0; n < 4; ++n) {
    as4[n] = a_src[ccol0 + n * 16];
    ad4[n] = a_dst[ccol0 + n * 16];
  }
  int p = bx * 2 + wc;
#pragma unroll
  for (int m = 0; m < 4; ++m) {
#pragma unroll
    for (int j = 0; j < 4; ++j) {
      float ps = acc[m][0][j] * as4[0] + acc[m][1][j] * as4[1] +
                 acc[m][2][j] * as4[2] + acc[m][3][j] * as4[3];
      float pd = acc[m][0][j] * ad4[0] + acc[m][1][j] * ad4[1] +
                 acc[m][2][j] * ad4[2] + acc[m][3][j] * ad4[3];
#pragma unroll
      for (int o = 1; o < 16; o <<= 1) {
        ps += __shfl_xor(ps, o, 64);
        pd += __shfl_xor(pd, o, 64);
      }
      int row = crow0 + m * 16 + j;
      if ((lane & 15) == 0 && row < M) {
        partS[(ll)p * M + row] = ps;
        partD[(ll)p * M + row] = pd;
      }
    }
  }
}

// sum the per-(col-block,wc) partials -> s_src/s_dst
__global__ void score_reduce_kernel(const float* __restrict__ partS,
                                    const float* __restrict__ partD,
                                    float* __restrict__ s_src, float* __restrict__ s_dst,
                                    int N, int NP) {
  int i = blockIdx.x * blockDim.x + threadIdx.x;
  if (i >= N) return;
  float a = 0.f, b = 0.f;
  for (int p = 0; p < NP; ++p) {
    a += partS[(ll)p * N + i];
    b += partD[(ll)p * N + i];
  }
  s_src[i] = a;
  s_dst[i] = b;
}

// ---------------- segment softmax + weighted aggregation (per node) ---------
// Single CSR traversal stashes logits in LDS; weights normalized in-place;
// pass 3 reads weights by LDS broadcast (no gather/exp in inner loop),
// unrolled x2 for memory-level parallelism. THREADS = DOUT/DPT exactly.
template <int DOUT, int HIN_BF16, int OUTSPLIT>
__global__ __launch_bounds__(DOUT == 1024 ? 256 : (DOUT == 512 ? 128 : 64))
void aggregate_kernel(const void* __restrict__ hv, const float* __restrict__ ssrc,
                      const float* __restrict__ sdst, const int* __restrict__ rowptr,
                      const int* __restrict__ csr, const float* __restrict__ bias,
                      float* __restrict__ outF, short* __restrict__ outH) {
  constexpr int THREADS = DOUT == 1024 ? 256 : (DOUT == 512 ? 128 : 64);
  constexpr int NW = THREADS / 64;
  constexpr int DPT = DOUT / THREADS;  // 4, 4, 2
  int node = blockIdx.x;
  int tid = threadIdx.x;
  int lane = tid & 63, wid = tid >> 6;
  int rs = rowptr[node], re = rowptr[node + 1];
  int nd = re - rs;
  float sd = sdst[node];
  __shared__ float red[4];
  __shared__ float wl[MAXD];

  bool fits = nd <= MAXD;
  float m = -1e30f;
  if (fits) {
    for (int i = tid; i < nd; i += THREADS) {
      float e = ssrc[csr[rs + i]] + sd;
      e = e > 0.f ? e : NEG_SLOPE * e;
      wl[i] = e;
      m = fmaxf(m, e);
    }
  } else {
    for (int i = tid; i < nd; i += THREADS) {
      float e = ssrc[csr[rs + i]] + sd;
      e = e > 0.f ? e : NEG_SLOPE * e;
      m = fmaxf(m, e);
    }
  }
#pragma unroll
  for (int o = 32; o > 0; o >>= 1) m = fmaxf(m, __shfl_xor(m, o, 64));
  if (NW > 1) {
    if (lane == 0) red[wid] = m;
    __syncthreads();
    m = red[0];
#pragma unroll
    for (int w = 1; w < NW; ++w) m = fmaxf(m, red[w]);
    __syncthreads();
  }

  float den = 0.f;
  if (fits) {
    for (int i = tid; i < nd; i += THREADS) den += __expf(wl[i] - m);
  } else {
    for (int i = tid; i < nd; i += THREADS) {
      float e = ssrc[csr[rs + i]] + sd;
      e = e > 0.f ? e : NEG_SLOPE * e;
      den += __expf(e - m);
    }
  }
#pragma unroll
  for (int o = 32; o > 0; o >>= 1) den += __shfl_xor(den, o, 64);
  if (NW > 1) {
    if (lane == 0) red[wid] = den;
    __syncthreads();
    den = red[0];
#pragma unroll
    for (int w = 1; w < NW; ++w) den += red[w];
  }
  float inv = 1.f / (den + EPS_F);

  if (fits) {
    for (int i = tid; i < nd; i += THREADS) wl[i] = __expf(wl[i] - m) * inv;
  }
  __syncthreads();

  // pass 3: weighted accumulate, DPT dims per thread
  int d = tid * DPT;
  float acc[DPT];
#pragma unroll
  for (int k = 0; k < DPT; ++k) acc[k] = 0.f;

  auto accum = [&](int s, float w) {
    if constexpr (DPT == 4) {
      if constexpr (HIN_BF16) {
        short4 qv = *(const short4*)((const unsigned short*)hv + (ll)s * DOUT + d);
        acc[0] += w * bf16_back((unsigned short)qv.x);
        acc[1] += w * bf16_back((unsigned short)qv.y);
        acc[2] += w * bf16_back((unsigned short)qv.z);
        acc[3] += w * bf16_back((unsigned short)qv.w);
      } else {
        float4 qv = *(const float4*)((const float*)hv + (ll)s * DOUT + d);
        acc[0] += w * qv.x; acc[1] += w * qv.y;
        acc[2] += w * qv.z; acc[3] += w * qv.w;
      }
    } else {
      if constexpr (HIN_BF16) {
        short2 qv = *(const short2*)((const unsigned short*)hv + (ll)s * DOUT + d);
        acc[0] += w * bf16_back((unsigned short)qv.x);
        acc[1] += w * bf16_back((unsigned short)qv.y);
      } else {
        float2 qv = *(const float2*)((const float*)hv + (ll)s * DOUT + d);
        acc[0] += w * qv.x; acc[1] += w * qv.y;
      }
    }
  };

  if (fits) {
    int i = 0;
    for (; i + 2 <= nd; i += 2) {
      int s0 = csr[rs + i], s1 = csr[rs + i + 1];
      float w0 = wl[i], w1 = wl[i + 1];
      accum(s0, w0);
      accum(s1, w1);
    }
    if (i < nd) accum(csr[rs + i], wl[i]);
  } else {
    for (int i = 0; i < nd; ++i) {
      int s = csr[rs + i];
      float e = ssrc[s] + sd;
      e = e > 0.f ? e : NEG_SLOPE * e;
      accum(s, __expf(e - m) * inv);
    }
  }

  // epilogue: bias (+ReLU) and store
  if constexpr (DPT == 4) {
    float4 bv = *(const float4*)&bias[d];
    float v0 = acc[0] + bv.x, v1 = acc[1] + bv.y, v2 = acc[2] + bv.z, v3 = acc[3] + bv.w;
    if constexpr (OUTSPLIT) {
      v0 = fmaxf(v0, 0.f); v1 = fmaxf(v1, 0.f); v2 = fmaxf(v2, 0.f); v3 = fmaxf(v3, 0.f);
      unsigned short h0 = bf16_of(v0), h1 = bf16_of(v1), h2 = bf16_of(v2), h3 = bf16_of(v3);
      short4 hp = make_short4((short)h0, (short)h1, (short)h2, (short)h3);
      short4 lp = make_short4((short)bf16_of(v0 - bf16_back(h0)),
                              (short)bf16_of(v1 - bf16_back(h1)),
                              (short)bf16_of(v2 - bf16_back(h2)),
                              (short)bf16_of(v3 - bf16_back(h3)));
      ll base = (ll)node * (2 * DOUT) + d;
      *(short4*)&outH[base] = hp;
      *(short4*)&outH[base + DOUT] = lp;
    } else {
      *(float4*)&outF[(ll)node * DOUT + d] = make_float4(v0, v1, v2, v3);
    }
  } else {
    float2 bv = *(const float2*)&bias[d];
    float v0 = acc[0] + bv.x, v1 = acc[1] + bv.y;
    if constexpr (OUTSPLIT) {
      v0 = fmaxf(v0, 0.f); v1 = fmaxf(v1, 0.f);
      unsigned short h0 = bf16_of(v0), h1 = bf16_of(v1);
      short2 hp = make_short2((short)h0, (short)h1);
      short2 lp = make_short2((short)bf16_of(v0 - bf16_back(h0)),
                              (short)bf16_of(v1 - bf16_back(h1)));
      ll base = (ll)node * (2 * DOUT) + d;
      *(short2*)&outH[base] = hp;
      *(short2*)&outH[base + DOUT] = lp;
    } else {
      *(float2*)&outF[(ll)node * DOUT + d] = make_float2(v0, v1);
    }
  }
}

// ---------------- row log_softmax (C == blockDim.x) ----------------
__global__ void log_softmax_kernel(const float* __restrict__ in, float* __restrict__ out,
                                   int C) {
  int row = blockIdx.x;
  int tid = threadIdx.x;
  int lane = tid & 63, wid = tid >> 6;
  __shared__ float red[2];
  float v = in[(ll)row * C + tid];
  float m = v;
#pragma unroll
  for (int o = 32; o > 0; o >>= 1) m = fmaxf(m, __shfl_xor(m, o, 64));
  if (lane == 0) red[wid] = m;
  __syncthreads();
  m = fmaxf(red[0], red[1]);
  __syncthreads();
  float ex = __expf(v - m);
  float s = ex;
#pragma unroll
  for (int o = 32; o > 0; o >>= 1) s += __shfl_xor(s, o, 64);
  if (lane == 0) red[wid] = s;
  __syncthreads();
  s = red[0] + red[1];
  out[(ll)row * C + tid] = v - m - logf(s);
}

// ---------------- launch ----------------
extern "C" void kernel_launch(void* const* d_in, const int* in_sizes, int n_in,
                              void* d_out, int out_size, void* d_ws, size_t ws_size,
                              hipStream_t stream) {
  const float* x = (const float*)d_in[0];
  const int* ew = (const int*)d_in[1];
  int N = in_sizes[0] / 256;
  int E = in_sizes[1] / 2;

  const float* W[4]   = {(const float*)d_in[2],  (const float*)d_in[6],
                         (const float*)d_in[10], (const float*)d_in[14]};
  const float* Asv[4] = {(const float*)d_in[3],  (const float*)d_in[7],
                         (const float*)d_in[11], (const float*)d_in[15]};
  const float* Adv[4] = {(const float*)d_in[4],  (const float*)d_in[8],
                         (const float*)d_in[12], (const float*)d_in[16]};
  const float* Bv[4]  = {(const float*)d_in[5],  (const float*)d_in[9],
                         (const float*)d_in[13], (const float*)d_in[17]};
  const int din[4]  = {256, 1024, 1024, 512};
  const int dout[4] = {1024, 1024, 512, 128};

  char* ws = (char*)d_ws;
  size_t off = 0;
  auto alloc = [&](size_t bytes) {
    void* p = ws + off;
    off += (bytes + 255) & ~(size_t)255;
    return p;
  };
  unsigned short* hB = (unsigned short*)alloc((size_t)N * 1024 * 2);  // bf16 h (layers 1-3)
  float* hF   = (float*)alloc((size_t)N * 128 * 4);                   // fp32 h (layer 4)
  short* bufP = (short*)alloc((size_t)N * 2048 * 2);
  short* bufQ = (short*)alloc((size_t)N * 2048 * 2);
  float* sF   = (float*)alloc((size_t)N * 128 * 4);
  float* s_src = (float*)alloc((size_t)N * 4);
  float* s_dst = (float*)alloc((size_t)N * 4);
  float* partS = (float*)alloc((size_t)16 * N * 4);
  float* partD = (float*)alloc((size_t)16 * N * 4);
  int* deg    = (int*)alloc((size_t)(N + 1) * 4);
  int* rowptr = (int*)alloc((size_t)(N + 1) * 4);
  int* cursor = (int*)alloc((size_t)(N + 1) * 4);
  int* csr    = (int*)alloc((size_t)(E + N) * 4);
  int* flag   = (int*)alloc(256);
  short* Bt[4];
  for (int l = 0; l < 4; ++l) Bt[l] = (short*)alloc((size_t)dout[l] * din[l] * 2);

  detect_int64_kernel<<<1, 256, 0, stream>>>((const unsigned int*)ew, E, flag);
  init_deg_kernel<<<(N + 255) / 256, 256, 0, stream>>>(deg, N);
  count_deg_kernel<<<(E + 255) / 256, 256, 0, stream>>>(ew, E, deg, flag);
  scan_kernel<<<1, 1024, 0, stream>>>(deg, rowptr, cursor, N);
  fill_kernel<<<(E + N + 255) / 256, 256, 0, stream>>>(ew, E, N, cursor, csr, flag);

  convert_x_kernel<<<(N * 256 + 255) / 256, 256, 0, stream>>>(x, bufP, N);
  for (int l = 0; l < 4; ++l) {
    dim3 cg(din[l] / 32, dout[l] / 32);
    convert_w_kernel<<<cg, 256, 0, stream>>>(W[l], Bt[l], din[l], dout[l]);
  }

  short* cur = bufP;
  short* nxt = bufQ;
  for (int l = 0; l < 4; ++l) {
    dim3 ggrid(dout[l] / 128, (N + 127) / 128);
    int NP = (dout[l] / 128) * 2;
    if (l < 3) {
      gemm_mfma_kernel<1><<<ggrid, 256, 0, stream>>>(cur, Bt[l], hB, Asv[l], Adv[l],
                                                     partS, partD, N, dout[l], din[l]);
    } else {
      gemm_mfma_kernel<0><<<ggrid, 256, 0, stream>>>(cur, Bt[l], hF, Asv[l], Adv[l],
                                                     partS, partD, N, dout[l], din[l]);
    }
    score_reduce_kernel<<<(N + 255) / 256, 256, 0, stream>>>(partS, partD, s_src, s_dst,
                                                             N, NP);
    if (l < 2) {
      aggregate_kernel<1024, 1, 1><<<N, 256, 0, stream>>>(hB, s_src, s_dst, rowptr, csr,
                                                          Bv[l], nullptr, nxt);
    } else if (l == 2) {
      aggregate_kernel<512, 1, 1><<<N, 128, 0, stream>>>(hB, s_src, s_dst, rowptr, csr,
                                                         Bv[l], nullptr, nxt);
    } else {
      aggregate_kernel<128, 0, 0><<<N, 64, 0, stream>>>(hF, s_src, s_dst, rowptr, csr,
                                                        Bv[l], sF, nullptr);
    }
    short* t = cur; cur = nxt; nxt = t;
  }
  log_softmax_kernel<<<N, 128, 0, stream>>>(sF, (float*)d_out, 128);
}